// Round 8
// baseline (209.791 us; speedup 1.0000x reference)
//
#include <hip/hip_runtime.h>
#include <hip/hip_bf16.h>

// MaskedAttention R12: barrier-free, LDS-free attn via 32x32x16 swapped-operand
// MFMA + in-register S-transpose (T12 mechanism).
// R11 post-mortem: FETCH 79->40MB (XCD chunk worked) but dur flat 60us ->
// attn is structure-latency-bound: the LDS S-transpose forces a per-jt 4-wave
// barrier; all blocks lockstep -> SIMD-wide simultaneous stalls. Fix: each
// wave owns an independent 32i x 32d tile. S = mfma_32x32x16(K',Q') puts
// i=lane&31 lane-local (verified m74/m101 layout); PV A-frag assembled
// in-register: 8 cvt_pk + 4 shfl_xor(32) + 8 selects. V consumed as bf16
// j-pair-packed vt2[j/2][d] u32 (feat-produced): 8 imm-offset loads/step.
// Zero LDS, zero barriers. kp/mask prefetch depth-1, V same-step.

#define B_ 16
#define L_ 576
#define H_ 12
#define D_ 64
#define M_ 8
#define NUM_STAB 1e-3f
#define RATIO 0.35355339059327373f  // 1/sqrt(M)

typedef __attribute__((ext_vector_type(8))) short short8;
typedef __attribute__((ext_vector_type(4))) float f32x4;
typedef __attribute__((ext_vector_type(16))) float f32x16;

union Pack {
    uint4 u4;
    short8 s8;
    unsigned u[4];
    unsigned short us[8];
};

__device__ inline unsigned short f2bf(float x) {  // RNE fp32 -> bf16 bits
    union { float f; unsigned u; } a; a.f = x;
    unsigned r = (a.u + 0x7FFFu + ((a.u >> 16) & 1u)) >> 16;
    return (unsigned short)r;
}
__device__ inline unsigned pk2(float lo, float hi) {  // v_cvt_pk_bf16_f32 (RNE)
    __hip_bfloat162 h = __float22bfloat162_rn(make_float2(lo, hi));
    union { __hip_bfloat162 b; unsigned u; } c; c.b = h;
    return c.u;
}
__device__ inline float bf2f(unsigned short u) {
    union { unsigned u; float f; } c; c.u = (unsigned)u << 16; return c.f;
}

// ws layout: cmask H*L f32 | w B*H*M f32 | qp bf16 | kp bf16 | vt2 u32
#define WS_W_OFF  (H_ * L_)
#define WS_QP_OFF (H_ * L_ + B_ * H_ * M_)
#define QP_ELEMS  ((size_t)B_ * H_ * L_ * M_)
#define VT2_PER_BH (288 * 64)   // (L/2) x D u32

// ---------------- kernel 1: features + cmask col-sums + vt2 (bf16 j-pair-packed V) ----------------
__global__ __launch_bounds__(256) void feat_kernel(const float* __restrict__ q,
                                                   const float* __restrict__ k,
                                                   const float* __restrict__ v,
                                                   const float* __restrict__ proj,
                                                   const float* __restrict__ mask,
                                                   unsigned short* __restrict__ qp,
                                                   unsigned short* __restrict__ kp,
                                                   float* __restrict__ cmask,
                                                   unsigned* __restrict__ vt2) {
    __shared__ float cred[4][16];
    const int lc = blockIdx.x, h = blockIdx.y, b = blockIdx.z, t = threadIdx.x;
    const int wv = t >> 6, l = t & 63, r8 = l >> 3, c8 = l & 7;
    const int row = lc * 32 + wv * 8 + r8;

    float4 pj0[8], pj1[8];
#pragma unroll
    for (int m = 0; m < 8; ++m) {
        pj0[m] = *(const float4*)(proj + m * 64 + c8 * 8);
        pj1[m] = *(const float4*)(proj + m * 64 + c8 * 8 + 4);
    }

#pragma unroll
    for (int s = 0; s < 2; ++s) {
        const float* src = s ? k : q;
        unsigned short* dst = s ? kp : qp;
        const float* xp = src + (((size_t)b * L_ + row) * H_ + h) * D_ + c8 * 8;
        float4 x0 = *(const float4*)xp;
        float4 x1 = *(const float4*)(xp + 4);
        x0.x *= RATIO; x0.y *= RATIO; x0.z *= RATIO; x0.w *= RATIO;
        x1.x *= RATIO; x1.y *= RATIO; x1.z *= RATIO; x1.w *= RATIO;
        float p[8];
#pragma unroll
        for (int m = 0; m < 8; ++m) {
            p[m] = x0.x * pj0[m].x + x0.y * pj0[m].y + x0.z * pj0[m].z + x0.w * pj0[m].w
                 + x1.x * pj1[m].x + x1.y * pj1[m].y + x1.z * pj1[m].z + x1.w * pj1[m].w;
        }
#pragma unroll
        for (int st = 1; st <= 4; st <<= 1) {
#pragma unroll
            for (int m = 0; m < 8; ++m) p[m] += __shfl_xor(p[m], st, 64);
        }
        float r = p[0];
        r = (c8 == 1) ? p[1] : r;
        r = (c8 == 2) ? p[2] : r;
        r = (c8 == 3) ? p[3] : r;
        r = (c8 == 4) ? p[4] : r;
        r = (c8 == 5) ? p[5] : r;
        r = (c8 == 6) ? p[6] : r;
        r = (c8 == 7) ? p[7] : r;
        r = fmaxf(r, 0.f) + NUM_STAB;
        dst[((size_t)(b * H_ + h) * L_ + row) * 8 + c8] = f2bf(r);
    }

    // ---- vt2 fill: vt2[bh][j2][d] = (bf16(V[2j2][d]) | bf16(V[2j2+1][d])<<16) ----
    {
        const int dv = t & 63, wv2 = t >> 6;
        unsigned* vw = vt2 + (size_t)(b * H_ + h) * VT2_PER_BH;
#pragma unroll
        for (int rr = 0; rr < 4; ++rr) {
            const int j2 = lc * 16 + rr * 4 + wv2;
            const float* vs = v + (((size_t)b * L_ + 2 * j2) * H_ + h) * D_ + dv;
            float v0 = vs[0], v1 = vs[H_ * D_];
            vw[(size_t)j2 * 64 + dv] = pk2(v0, v1);
        }
    }

    if (b < 2) {
        const int c = t & 15, rg = t >> 4;
        const int col0 = lc * 32 + b * 16;
        const float* mb = mask + (size_t)h * L_ * L_ + col0 + c;
        float a = 0.f;
#pragma unroll 4
        for (int k2 = 0; k2 < 36; ++k2) a += mb[(size_t)(rg + 16 * k2) * L_];
        a += __shfl_xor(a, 16, 64);
        a += __shfl_xor(a, 32, 64);
        if ((l >> 4) == 0) cred[wv][c] = a;
        __syncthreads();
        if (t < 16) cmask[h * L_ + col0 + t] = cred[0][t] + cred[1][t] + cred[2][t] + cred[3][t];
    }
}

// ---------------- kernel 2: w[b,h,m] = sum_j cmask[h,j] * k'[b,h,j,m] ----------------
__global__ __launch_bounds__(64) void wsum_kernel(const unsigned short* __restrict__ kp,
                                                  const float* __restrict__ cmask,
                                                  float* __restrict__ wbuf) {
    const int bh = blockIdx.x, lx = threadIdx.x;
    const int h = bh % H_;
    const unsigned short* kpb = kp + (size_t)bh * L_ * 8;
    const float* cm = cmask + h * L_;
    float a[8] = {0.f, 0.f, 0.f, 0.f, 0.f, 0.f, 0.f, 0.f};
    for (int j = lx; j < L_; j += 64) {
        const float c = cm[j];
        Pack pk; pk.u4 = *(const uint4*)(kpb + (size_t)j * 8);
#pragma unroll
        for (int m = 0; m < 8; ++m) a[m] += c * bf2f(pk.us[m]);
    }
#pragma unroll
    for (int st = 1; st < 64; st <<= 1) {
#pragma unroll
        for (int m = 0; m < 8; ++m) a[m] += __shfl_xor(a[m], st, 64);
    }
    float r = a[0];
    r = (lx == 1) ? a[1] : r;
    r = (lx == 2) ? a[2] : r;
    r = (lx == 3) ? a[3] : r;
    r = (lx == 4) ? a[4] : r;
    r = (lx == 5) ? a[5] : r;
    r = (lx == 6) ? a[6] : r;
    r = (lx == 7) ? a[7] : r;
    if (lx < 8) wbuf[(size_t)bh * 8 + lx] = r;
}

// ---------------- kernel 3: attention, one independent 32i x 32d tile per wave ----------------
// grid 1728 (XCD-chunked vid), block 256 = 4 independent waves (iw=wv>>1, dw=wv&1).
// Per 32-j step: S = mfma_32x32x16(K'frag, Q'frag) [lane: col i=l&31, rows j by reg];
// s~ = S*mask; cvt_pk -> 8 u32; half-exchange (4 shfl_xor + 8 sel) -> 2 PV A-frags;
// acc = mfma(A0,V0,acc); acc = mfma(A1,V1,acc). No LDS, no barrier.
__global__ __launch_bounds__(256, 4) void attn_kernel(const float* __restrict__ mask,
                                                      const unsigned short* __restrict__ qp,
                                                      const unsigned short* __restrict__ kp,
                                                      const unsigned* __restrict__ vt2,
                                                      const float* __restrict__ wbuf,
                                                      float* __restrict__ out) {
    const int t = threadIdx.x;
    const int n = blockIdx.x;
    const int vid = (n & 7) * 216 + (n >> 3);   // XCD-chunked (R11, keeps FETCH win)
    const int b = vid & 15;
    const int g = vid >> 4;
    const int it = g % 9, h = g / 9;

    const int wv = t >> 6, ln = t & 63, li = ln & 31, hx = ln >> 5;
    const bool hi = (hx != 0);
    const int iw = wv >> 1, dw = wv & 1;
    const int i0 = it * 64 + iw * 32;
    const int d0 = dw * 32;
    const int bh = b * H_ + h;

    const unsigned short* kpb = kp + (size_t)bh * L_ * 8;
    const float* mrow = mask + (size_t)h * L_ * L_ + (size_t)(i0 + li) * L_ + 4 * hx;
    const unsigned* vp = vt2 + (size_t)bh * VT2_PER_BH + hx * (4 * 64) + d0 + li;

    // loop-invariant Q' B-frag: lanes hx==0 hold Q'[i0+li][m0..7]; hx==1 zero (k=8..15 pad)
    short8 Bq;
    {
        Pack pk; pk.u4 = make_uint4(0, 0, 0, 0);
        if (!hi) pk.u4 = *(const uint4*)(qp + ((size_t)bh * L_ + i0 + li) * 8);
        Bq = pk.s8;
    }

    f32x16 acc = {};
    const f32x16 zz = {};

    uint4 kbuf[2];
    float4 mbuf[2][4];
    kbuf[0] = make_uint4(0, 0, 0, 0);
    kbuf[1] = make_uint4(0, 0, 0, 0);

    // prologue: jt=0 K' + mask
    if (!hi) kbuf[0] = *(const uint4*)(kpb + (size_t)li * 8);
    mbuf[0][0] = *(const float4*)(mrow + 0);
    mbuf[0][1] = *(const float4*)(mrow + 8);
    mbuf[0][2] = *(const float4*)(mrow + 16);
    mbuf[0][3] = *(const float4*)(mrow + 24);

#pragma unroll
    for (int jt = 0; jt < 18; ++jt) {
        const int p = jt & 1, np = p ^ 1;

        // ---- V for THIS step (8 u32, one pointer + imm offsets) ----
        const unsigned* vq = vp + (size_t)jt * 1024;
        unsigned vb0 = vq[0],   vb1 = vq[64],  vb2 = vq[128], vb3 = vq[192];
        unsigned vb4 = vq[512], vb5 = vq[576], vb6 = vq[640], vb7 = vq[704];

        // ---- prefetch jt+1 K' + mask (depth-1) ----
        const int j1 = ((jt < 17) ? jt + 1 : 0) * 32;
        if (!hi) kbuf[np] = *(const uint4*)(kpb + (size_t)(j1 + li) * 8);
        mbuf[np][0] = *(const float4*)(mrow + j1 + 0);
        mbuf[np][1] = *(const float4*)(mrow + j1 + 8);
        mbuf[np][2] = *(const float4*)(mrow + j1 + 16);
        mbuf[np][3] = *(const float4*)(mrow + j1 + 24);

        // ---- phase A: S[j 32][i 32], i = lane-local ----
        Pack ka; ka.u4 = kbuf[p];
        f32x16 S = __builtin_amdgcn_mfma_f32_32x32x16_bf16(ka.s8, Bq, zz, 0, 0, 0);

        // ---- mask mul (j per reg: (r&3)+8*(r>>2)+4*hx) + pack to bf16 ----
        unsigned pk_[8];
#pragma unroll
        for (int r4 = 0; r4 < 4; ++r4) {
            const float4 m4 = mbuf[p][r4];
            pk_[2 * r4]     = pk2(S[4 * r4 + 0] * m4.x, S[4 * r4 + 1] * m4.y);
            pk_[2 * r4 + 1] = pk2(S[4 * r4 + 2] * m4.z, S[4 * r4 + 3] * m4.w);
        }

        // ---- in-register half-exchange -> PV A-frags ----
        unsigned q0 = hi ? pk_[0] : pk_[2];
        unsigned q1 = hi ? pk_[1] : pk_[3];
        unsigned q2 = hi ? pk_[4] : pk_[6];
        unsigned q3 = hi ? pk_[5] : pk_[7];
        unsigned s0 = (unsigned)__shfl_xor((int)q0, 32, 64);
        unsigned s1 = (unsigned)__shfl_xor((int)q1, 32, 64);
        unsigned s2 = (unsigned)__shfl_xor((int)q2, 32, 64);
        unsigned s3 = (unsigned)__shfl_xor((int)q3, 32, 64);
        Pack A0, A1, V0, V1;
        A0.u[0] = hi ? s0 : pk_[0];
        A0.u[1] = hi ? s1 : pk_[1];
        A0.u[2] = hi ? pk_[2] : s0;
        A0.u[3] = hi ? pk_[3] : s1;
        A1.u[0] = hi ? s2 : pk_[4];
        A1.u[1] = hi ? s3 : pk_[5];
        A1.u[2] = hi ? pk_[6] : s2;
        A1.u[3] = hi ? pk_[7] : s3;
        V0.u[0] = vb0; V0.u[1] = vb1; V0.u[2] = vb2; V0.u[3] = vb3;
        V1.u[0] = vb4; V1.u[1] = vb5; V1.u[2] = vb6; V1.u[3] = vb7;

        // ---- phase B: O += S~^T . V ----
        acc = __builtin_amdgcn_mfma_f32_32x32x16_bf16(A0.s8, V0.s8, acc, 0, 0, 0);
        acc = __builtin_amdgcn_mfma_f32_32x32x16_bf16(A1.s8, V1.s8, acc, 0, 0, 0);
    }

    // ---- epilogue: n_i = q'_i . w; out[i, d0+li] = acc/n ----
    const float* wp = wbuf + (size_t)bh * 8;
    const float4 w0 = *(const float4*)wp;
    const float4 w1 = *(const float4*)(wp + 4);
    Pack pq;
    pq.u4 = *(const uint4*)(qp + ((size_t)bh * L_ + i0 + li) * 8);
    float nn = bf2f(pq.us[0]) * w0.x + bf2f(pq.us[1]) * w0.y +
               bf2f(pq.us[2]) * w0.z + bf2f(pq.us[3]) * w0.w +
               bf2f(pq.us[4]) * w1.x + bf2f(pq.us[5]) * w1.y +
               bf2f(pq.us[6]) * w1.z + bf2f(pq.us[7]) * w1.w;
    float ivn = 1.0f / nn;   // lane li holds 1/n for i = i0+li (both halves)

    float* ob = out + (((size_t)b * L_ + i0) * H_ + h) * D_ + d0 + li;
#pragma unroll
    for (int r = 0; r < 16; ++r) {
        const int row = (r & 3) + 8 * (r >> 2) + 4 * hx;
        float iv = __shfl(ivn, row, 64);
        ob[(size_t)row * (H_ * D_)] = acc[r] * iv;
    }
}

extern "C" void kernel_launch(void* const* d_in, const int* in_sizes, int n_in,
                              void* d_out, int out_size, void* d_ws, size_t ws_size,
                              hipStream_t stream) {
    const float* q    = (const float*)d_in[0];
    const float* k    = (const float*)d_in[1];
    const float* v    = (const float*)d_in[2];
    const float* proj = (const float*)d_in[3];
    const float* mask = (const float*)d_in[4];
    float* out = (float*)d_out;

    float* ws = (float*)d_ws;
    float* cmask = ws;
    float* wbuf  = ws + WS_W_OFF;
    unsigned short* qp_w = (unsigned short*)(ws + WS_QP_OFF);
    unsigned short* kp_w = qp_w + QP_ELEMS;
    unsigned* vt2_w = (unsigned*)(kp_w + QP_ELEMS);   // B*H*288*64 u32 = 14.2 MB

    feat_kernel<<<dim3(L_ / 32, H_, B_), 256, 0, stream>>>(q, k, v, proj, mask, qp_w, kp_w, cmask, vt2_w);
    wsum_kernel<<<B_ * H_, 64, 0, stream>>>(kp_w, cmask, wbuf);
    attn_kernel<<<1728, 256, 0, stream>>>(mask, qp_w, kp_w, vt2_w, wbuf, out);
}

// Round 9
// 184.272 us; speedup vs baseline: 1.1385x; 1.1385x over previous
//
#include <hip/hip_runtime.h>
#include <hip/hip_bf16.h>

// MaskedAttention R13: R0 (the 182.75us config - best e2e of 9 rounds) plus
// exactly two isolated attn deltas:
//  (1) prefetch moved AFTER __syncthreads (consumers all pre-barrier, so the
//      barrier's vmcnt(0) drain is naturally satisfied; the only transferable
//      ingredient of R6's 54.5us),
//  (2) XCD-chunked b-minor block remap (R11-proven: FETCH 79->40MB; one
//      (h,it) mask slice = 1 HBM fetch + 15 L2 hits on its XCD).
// Everything else R0-verbatim: 2 kernels, 3.6MB ws, cms in-attn normalizer
// (no wsum launch), TJ=64 slab-dbuf Bt, swizzled cms b32 broadcasts.
// 9-round ledger: every precompute scheme (vt/vt2/wsum) moved cost to
// feat/ws-poison/launches at >=1:1; R0's fixed side is the cheapest measured.

#define B_ 16
#define L_ 576
#define H_ 12
#define D_ 64
#define M_ 8
#define NUM_STAB 1e-3f
#define RATIO 0.35355339059327373f  // 1/sqrt(M)

typedef __attribute__((ext_vector_type(8))) short short8;
typedef __attribute__((ext_vector_type(4))) float f32x4;

union Pack {
    uint4 u4;
    short8 s8;
    uint2 u2[2];
    unsigned u[4];
    unsigned short us[8];
};

__device__ inline unsigned short f2bf(float x) {  // RNE fp32 -> bf16 bits
    union { float f; unsigned u; } a; a.f = x;
    unsigned r = (a.u + 0x7FFFu + ((a.u >> 16) & 1u)) >> 16;
    return (unsigned short)r;
}
__device__ inline unsigned pk2(float lo, float hi) {  // v_cvt_pk_bf16_f32 (RNE)
    __hip_bfloat162 h = __float22bfloat162_rn(make_float2(lo, hi));
    union { __hip_bfloat162 b; unsigned u; } c; c.b = h;
    return c.u;
}

// ws layout: cmask H*L floats, then qp/kp as bf16 [B,H,L,M]
#define WS_QP_OFF (H_ * L_)
#define QP_ELEMS  ((size_t)B_ * H_ * L_ * M_)

// ---------------- kernel 1: features (bf16 out) + fused cmask col-sums ----------------
__global__ __launch_bounds__(256) void feat_kernel(const float* __restrict__ q,
                                                   const float* __restrict__ k,
                                                   const float* __restrict__ proj,
                                                   const float* __restrict__ mask,
                                                   unsigned short* __restrict__ qp,
                                                   unsigned short* __restrict__ kp,
                                                   float* __restrict__ cmask) {
    __shared__ float cred[4][16];
    const int lc = blockIdx.x, h = blockIdx.y, b = blockIdx.z, t = threadIdx.x;
    const int wv = t >> 6, l = t & 63, r8 = l >> 3, c8 = l & 7;
    const int row = lc * 32 + wv * 8 + r8;

    float4 pj0[8], pj1[8];
#pragma unroll
    for (int m = 0; m < 8; ++m) {
        pj0[m] = *(const float4*)(proj + m * 64 + c8 * 8);
        pj1[m] = *(const float4*)(proj + m * 64 + c8 * 8 + 4);
    }

#pragma unroll
    for (int s = 0; s < 2; ++s) {
        const float* src = s ? k : q;
        unsigned short* dst = s ? kp : qp;
        const float* xp = src + (((size_t)b * L_ + row) * H_ + h) * D_ + c8 * 8;
        float4 x0 = *(const float4*)xp;
        float4 x1 = *(const float4*)(xp + 4);
        x0.x *= RATIO; x0.y *= RATIO; x0.z *= RATIO; x0.w *= RATIO;
        x1.x *= RATIO; x1.y *= RATIO; x1.z *= RATIO; x1.w *= RATIO;
        float p[8];
#pragma unroll
        for (int m = 0; m < 8; ++m) {
            p[m] = x0.x * pj0[m].x + x0.y * pj0[m].y + x0.z * pj0[m].z + x0.w * pj0[m].w
                 + x1.x * pj1[m].x + x1.y * pj1[m].y + x1.z * pj1[m].z + x1.w * pj1[m].w;
        }
#pragma unroll
        for (int st = 1; st <= 4; st <<= 1) {
#pragma unroll
            for (int m = 0; m < 8; ++m) p[m] += __shfl_xor(p[m], st, 64);
        }
        float r = p[0];
        r = (c8 == 1) ? p[1] : r;
        r = (c8 == 2) ? p[2] : r;
        r = (c8 == 3) ? p[3] : r;
        r = (c8 == 4) ? p[4] : r;
        r = (c8 == 5) ? p[5] : r;
        r = (c8 == 6) ? p[6] : r;
        r = (c8 == 7) ? p[7] : r;
        r = fmaxf(r, 0.f) + NUM_STAB;
        dst[((size_t)(b * H_ + h) * L_ + row) * 8 + c8] = f2bf(r);
    }

    if (b < 2) {
        const int c = t & 15, rg = t >> 4;
        const int col0 = lc * 32 + b * 16;
        const float* mb = mask + (size_t)h * L_ * L_ + col0 + c;
        float a = 0.f;
#pragma unroll 4
        for (int k2 = 0; k2 < 36; ++k2) a += mb[(size_t)(rg + 16 * k2) * L_];
        a += __shfl_xor(a, 16, 64);
        a += __shfl_xor(a, 32, 64);
        if ((l >> 4) == 0) cred[wv][c] = a;
        __syncthreads();
        if (t < 16) cmask[h * L_ + col0 + t] = cred[0][t] + cred[1][t] + cred[2][t] + cred[3][t];
    }
}

// ---------------- kernel 2: main attention (pure bf16 MFMA, TJ=64) ----------------
// grid 1728 (XCD-chunked), block 256 (4 waves). Per block: 64 i x 64 d; 9 j-tiles of 64.
// XCD chunking: hw XCD = n%8; vid=(n&7)*216+(n>>3) gives each XCD a contiguous
// 216-vid chunk; vid is b-minor so one (h,it) mask slice's 16 b-blocks run
// consecutively on one XCD (1 HBM fetch + 15 L2 hits).
// Per jt: phaseA (4 subtiles of 16 j) -> V->Bt[slab] -> normalizer+Sp ->
// barrier (all globals consumed pre-barrier -> vmcnt drain free) ->
// prefetch jt+1 (overlaps phase B) -> phase B (8 MFMA).
__global__ __launch_bounds__(256, 4) void attn_kernel(const float* __restrict__ v,
                                                      const float* __restrict__ mask,
                                                      const unsigned short* __restrict__ qp,
                                                      const unsigned short* __restrict__ kp,
                                                      const float* __restrict__ cmask,
                                                      float* __restrict__ out) {
    __shared__ __align__(16) unsigned short Sp[4 * 16 * 72];   // 9216 B, per-wave chunks
    __shared__ __align__(16) unsigned short Bt[2][64 * 72];    // 18432 B
    __shared__ float cms[576];                                 // swizzled [p=16][jt=9][kq=4]

    const int t = threadIdx.x;
    const int n = blockIdx.x;
    const int vid = (n & 7) * 216 + (n >> 3);   // XCD-chunked virtual id (bijective: 1728=8*216)
    const int b = vid & 15;
    const int g = vid >> 4;                     // g = h*9 + it in [0,108)
    const int it = g % 9, h = g / 9;
    const int i0 = it * 64;

    const int wv = t >> 6, l = t & 63, c15 = l & 15, kq = l >> 4;

    // swizzled cms staging: cms[p*36 + jt*4 + kq] = cmask[h, jt*64 + 16*(p>>2) + 4*kq + (p&3)]
    {
        const float* cmg = cmask + h * L_;
#pragma unroll
        for (int rep = 0; rep < 3; ++rep) {
            int idx = t + rep * 256;
            if (idx < 576) {
                int p = idx / 36, rem = idx - p * 36;
                int jt9 = rem >> 2, kqi = rem & 3;
                int j = jt9 * 64 + ((p >> 2) << 4) + 4 * kqi + (p & 3);
                cms[idx] = cmg[j];
            }
        }
    }

    const float* maskbase = mask + (size_t)h * L_ * L_ + (size_t)(i0 + 16 * wv + c15) * L_;
    const unsigned short* kpb = kp + (size_t)(b * H_ + h) * L_ * 8;
    const float* vb = v + ((size_t)b * L_ * H_ + h) * D_ + l;

    // loop-invariant Q' B-fragment (kq==0 lanes hold Q'[i0+16wv+c15][m0..7])
    short8 Bq;
    {
        Pack pk; pk.u4 = make_uint4(0, 0, 0, 0);
        if (kq == 0) {
            const unsigned short* qpb = qp + ((size_t)(b * H_ + h) * L_ + i0 + 16 * wv + c15) * 8;
            pk.u4 = *(const uint4*)qpb;
        }
        Bq = pk.s8;
    }

    unsigned short* SpW = Sp + wv * 16 * 72;

    f32x4 acc0 = {0.f, 0.f, 0.f, 0.f}, acc1 = acc0, acc2 = acc0, acc3 = acc0;
    float nacc = 0.f;

    // prefetch tile 0
    float vf[16];
    float4 mv[4];
    uint4 kraw0 = make_uint4(0, 0, 0, 0), kraw1 = kraw0;
    {
#pragma unroll
        for (int qv = 0; qv < 16; ++qv) vf[qv] = vb[(size_t)(16 * wv + qv) * (H_ * D_)];
#pragma unroll
        for (int T = 0; T < 4; ++T) mv[T] = *(const float4*)(maskbase + 16 * T + 4 * kq);
        if (kq < 2) {
            kraw0 = *(const uint4*)(kpb + (size_t)(16 * kq + c15) * 8);
            kraw1 = *(const uint4*)(kpb + (size_t)(32 + 16 * kq + c15) * 8);
        }
    }

    __syncthreads();  // cms ready

    for (int jt = 0; jt < 9; ++jt) {
        const int j0 = jt * 64;
        const int slab = jt & 1;

        // ---- phase A: 4 subtiles of 16 j ----
        f32x4 s[4];
        const f32x4 zz = {0.f, 0.f, 0.f, 0.f};
#pragma unroll
        for (int hh = 0; hh < 2; ++hh) {
            uint4 kr = hh ? kraw1 : kraw0;
            Pack a0, a1;
            a1.u[0] = __shfl_down(kr.x, 16, 64);
            a1.u[1] = __shfl_down(kr.y, 16, 64);
            a1.u[2] = __shfl_down(kr.z, 16, 64);
            a1.u[3] = __shfl_down(kr.w, 16, 64);
            if (kq == 0) {
                a0.u4 = kr;
            } else {
                a0.u4 = make_uint4(0, 0, 0, 0);
                a1.u4 = make_uint4(0, 0, 0, 0);
            }
            s[2 * hh]     = __builtin_amdgcn_mfma_f32_16x16x32_bf16(a0.s8, Bq, zz, 0, 0, 0);
            s[2 * hh + 1] = __builtin_amdgcn_mfma_f32_16x16x32_bf16(a1.s8, Bq, zz, 0, 0, 0);
        }

        // ---- V -> Bt[slab] (hw packed cvt) ----
        {
            Pack p0, p1;
#pragma unroll
            for (int qv = 0; qv < 4; ++qv) p0.u[qv] = pk2(vf[2 * qv], vf[2 * qv + 1]);
#pragma unroll
            for (int qv = 0; qv < 4; ++qv) p1.u[qv] = pk2(vf[8 + 2 * qv], vf[9 + 2 * qv]);
            *(uint4*)&Bt[slab][l * 72 + 16 * wv] = p0.u4;
            *(uint4*)&Bt[slab][l * 72 + 16 * wv + 8] = p1.u4;
        }

        // ---- normalizer (raw S x swizzled cms, b32 broadcasts) + masked-S store ----
#pragma unroll
        for (int T = 0; T < 4; ++T) {
            const float* cp = &cms[(T * 4) * 36 + jt * 4 + kq];
            float c0 = cp[0], c1 = cp[36], c2 = cp[72], c3 = cp[108];
            nacc += c0 * s[T][0] + c1 * s[T][1] + c2 * s[T][2] + c3 * s[T][3];
            float4 m4 = mv[T];
            uint2 st2;
            st2.x = pk2(s[T][0] * m4.x, s[T][1] * m4.y);
            st2.y = pk2(s[T][2] * m4.z, s[T][3] * m4.w);
            *(uint2*)&SpW[c15 * 72 + 16 * T + 4 * kq] = st2;
        }

        __syncthreads();  // Bt[slab] + Sp ready; all globals already consumed

        // ---- prefetch next tile AFTER barrier (overlaps phase B; consumed pre-barrier) ----
        {
            const int jn = (jt < 8) ? j0 + 64 : 0;
#pragma unroll
            for (int qv = 0; qv < 16; ++qv) vf[qv] = vb[(size_t)(jn + 16 * wv + qv) * (H_ * D_)];
#pragma unroll
            for (int T = 0; T < 4; ++T) mv[T] = *(const float4*)(maskbase + jn + 16 * T + 4 * kq);
            if (kq < 2) {
                kraw0 = *(const uint4*)(kpb + (size_t)(jn + 16 * kq + c15) * 8);
                kraw1 = *(const uint4*)(kpb + (size_t)(jn + 32 + 16 * kq + c15) * 8);
            }
        }

        // ---- phase B: O += S.V over K=64 (2 chunks) ----
        {
            short8 As0 = *(const short8*)&SpW[c15 * 72 + kq * 8];
            short8 As1 = *(const short8*)&SpW[c15 * 72 + 32 + kq * 8];
#pragma unroll
            for (int di = 0; di < 4; ++di) {
                const unsigned short* bp = &Bt[slab][(16 * di + c15) * 72 + kq * 8];
                short8 B0 = *(const short8*)bp;
                short8 B1 = *(const short8*)(bp + 32);
                f32x4* ap = (di == 0) ? &acc0 : (di == 1) ? &acc1 : (di == 2) ? &acc2 : &acc3;
                *ap = __builtin_amdgcn_mfma_f32_16x16x32_bf16(As0, B0, *ap, 0, 0, 0);
                *ap = __builtin_amdgcn_mfma_f32_16x16x32_bf16(As1, B1, *ap, 0, 0, 0);
            }
        }
    }

    // normalizer reduce over kq-copies
    nacc += __shfl_xor(nacc, 16, 64);
    nacc += __shfl_xor(nacc, 32, 64);
    float iv[4];
#pragma unroll
    for (int r = 0; r < 4; ++r) iv[r] = 1.0f / __shfl(nacc, 4 * kq + r, 64);

    float* ob = out + (((size_t)b * L_ + i0 + 16 * wv + 4 * kq) * H_ + h) * D_ + c15;
    const f32x4 aa[4] = {acc0, acc1, acc2, acc3};
#pragma unroll
    for (int di = 0; di < 4; ++di)
#pragma unroll
        for (int r = 0; r < 4; ++r)
            ob[(size_t)r * (H_ * D_) + 16 * di] = aa[di][r] * iv[r];
}

extern "C" void kernel_launch(void* const* d_in, const int* in_sizes, int n_in,
                              void* d_out, int out_size, void* d_ws, size_t ws_size,
                              hipStream_t stream) {
    const float* q    = (const float*)d_in[0];
    const float* k    = (const float*)d_in[1];
    const float* v    = (const float*)d_in[2];
    const float* proj = (const float*)d_in[3];
    const float* mask = (const float*)d_in[4];
    float* out = (float*)d_out;

    float* ws = (float*)d_ws;
    float* cmask = ws;
    unsigned short* qp_w = (unsigned short*)(ws + WS_QP_OFF);
    unsigned short* kp_w = qp_w + QP_ELEMS;

    feat_kernel<<<dim3(L_ / 32, H_, B_), 256, 0, stream>>>(q, k, proj, mask, qp_w, kp_w, cmask);
    attn_kernel<<<1728, 256, 0, stream>>>(v, mask, qp_w, kp_w, cmask, out);
}